// Round 12
// baseline (138.300 us; speedup 1.0000x reference)
//
#include <hip/hip_runtime.h>

typedef _Float16 f16;
typedef __attribute__((ext_vector_type(8))) _Float16 f16x8;
typedef __attribute__((ext_vector_type(4))) float f32x4;
typedef unsigned int u32;

#define S_      4
#define NPER    12500
#define NF      1024
#define HID     256
#define NSTRUCT 500
#define TM      96

#define GLB __attribute__((address_space(1)))
#define AS3 __attribute__((address_space(3)))

#define WAIT_VM(N)  asm volatile("s_waitcnt vmcnt(" #N ")" ::: "memory")
#define WAIT_LGKM() asm volatile("s_waitcnt lgkmcnt(0)" ::: "memory")
#define SCHED0()    __builtin_amdgcn_sched_barrier(0)
#define BARRIER()   do { __builtin_amdgcn_s_barrier(); SCHED0(); } while (0)

// ---------------------------------------------------------------------------
// Fused weight transpose + fp32->fp16 (all 3 layers, 1 launch) -- unchanged.
// ---------------------------------------------------------------------------
__global__ __launch_bounds__(256) void transpose_all_kernel(
    const float* __restrict__ W1, const float* __restrict__ W2,
    const float* __restrict__ W3,
    f16* __restrict__ w1t, f16* __restrict__ w2t, f16* __restrict__ w3t)
{
  const int z = blockIdx.z;            // layer*4 + species
  const int layer = z >> 2, sp = z & 3;
  const float* in; f16* out; int K;
  if (layer == 0)      { in = W1; out = w1t; K = NF;  }
  else if (layer == 1) { in = W2; out = w2t; K = HID; }
  else                 { in = W3; out = w3t; K = HID; }
  if (blockIdx.x * 64 >= K) return;

  __shared__ float tile[64][65];
  const float* inp = in + (size_t)sp * K * HID;
  f16* outp = out + (size_t)sp * K * HID;
  const int k0 = blockIdx.x * 64;
  const int n0 = blockIdx.y * 64;
  const int t = threadIdx.x;
  {
    const int lk = t >> 2;
    const int nq = (t & 3) * 16;
    const float* src = inp + (size_t)(k0 + lk) * HID + n0 + nq;
    #pragma unroll
    for (int i = 0; i < 4; ++i) {
      float4 v = *(const float4*)(src + i * 4);
      tile[lk][nq + i * 4 + 0] = v.x;
      tile[lk][nq + i * 4 + 1] = v.y;
      tile[lk][nq + i * 4 + 2] = v.z;
      tile[lk][nq + i * 4 + 3] = v.w;
    }
  }
  __syncthreads();
  {
    const int ln = t >> 2;
    const int kq = (t & 3) * 16;
    f16* dst = outp + (size_t)(n0 + ln) * K + k0 + kq;
    f16x8 a, b;
    #pragma unroll
    for (int j = 0; j < 8; ++j) a[j] = (f16)tile[kq + j][ln];
    #pragma unroll
    for (int j = 0; j < 8; ++j) b[j] = (f16)tile[kq + 8 + j][ln];
    *(f16x8*)dst = a;
    *(f16x8*)(dst + 8) = b;
  }
}

// ---------------------------------------------------------------------------
// Fused MLP R19 = R18 (TM=96, 1.02 dispatch rounds) + VMEM ISSUE-ORDER
// PINNING: sched_barrier(0) after every VMEM-issuing group, so every manual
// WAIT_VM(N) ledger is sound by construction (R18's suspected failure: the
// scheduler permuting independent pa loads vs global_load_lds under high
// register pressure, leaving gll writes in flight at MFMA-read time).
// Structure otherwise identical to R18 (R17 chassis at TM=96):
//  - Grid 4 x 131 = 524 blocks vs 512 resident slots (1.02 rounds).
//  - Quad aS (4 x 12 KB), single wave-private bS 32 KB, barrier every 2
//    phases, 2-set pa rotation, steady VM(6).
//  - Hidden: hL [96][256] 48 KB overlay; wH 2 x 16 KB over dead bS, VM(4).
// ---------------------------------------------------------------------------

__device__ __forceinline__ void zero_acc(f32x4 (&acc)[6][4]) {
  #pragma unroll
  for (int a = 0; a < 6; ++a)
    #pragma unroll
    for (int b = 0; b < 4; ++b)
      #pragma unroll
      for (int j = 0; j < 4; ++j) acc[a][b][j] = 0.f;
}

// L1 weights: bS [256 n][8 slots of 16B]; phys slot p at row r holds k-slot
// p^(r&7). Wave w stages rows w*64..+63 -- exactly the rows it alone reads.
__device__ __forceinline__ void stage_w64(char* bS, const char* wbase, int c,
                                          int w, int lane)
{
  #pragma unroll
  for (int i = 0; i < 8; ++i) {
    const int seg  = w * 8 + i;                 // 0..31
    const int rloc = lane >> 3;                 // 0..7
    const int p    = lane & 7;                  // phys 16B slot
    const int row  = seg * 8 + rloc;            // 0..255
    const int slog = p ^ rloc;                  // logical k-slot (row&7 == rloc)
    const char* gp = wbase + (size_t)row * (NF * 2) + (size_t)c * 128 + slog * 16;
    char* lp = bS + seg * 1024;                 // wave-uniform base
    __builtin_amdgcn_global_load_lds((const GLB u32*)gp, (AS3 u32*)lp, 16, 0, 0);
  }
}

// Hidden weights: [256 n][32 k], phys slot = log ^ ((row>>1)&3). Self-staged.
__device__ __forceinline__ void stage_w32(char* wS, const char* wbase, int c,
                                          int w, int lane)
{
  #pragma unroll
  for (int i = 0; i < 4; ++i) {
    const int seg = w * 4 + i;                  // 0..15
    const int row = seg * 16 + (lane >> 2);     // 0..255
    const int kbp = lane & 3;
    const int kb  = kbp ^ ((row >> 1) & 3);
    const char* gp = wbase + (size_t)row * (HID * 2) + c * 64 + kb * 16;
    char* lp = wS + seg * 1024;
    __builtin_amdgcn_global_load_lds((const GLB u32*)gp, (AS3 u32*)lp, 16, 0, 0);
  }
}

// Features prefetch: 3 units/thread, unit i: row (t+256i)>>3, slot t&7.
__device__ __forceinline__ void load_pa96(float4 (&pa)[6],
                                          const float* const (&agp)[3], int c)
{
  #pragma unroll
  for (int i = 0; i < 3; ++i) {
    pa[2*i]   = *(const float4*)(agp[i] + (size_t)c * 64);
    pa[2*i+1] = *(const float4*)(agp[i] + (size_t)c * 64 + 4);
  }
}

// Features chunk [96 r][64 k] fp32->fp16 into aS (3 ds_write_b128/thread).
__device__ __forceinline__ void stage_feat96(char* aS, const float4 (&pa)[6],
                                             const u32 (&aof)[3])
{
  #pragma unroll
  for (int i = 0; i < 3; ++i) {
    f16x8 hv;
    const float4 lo = pa[2*i], hi = pa[2*i+1];
    hv[0]=(f16)lo.x; hv[1]=(f16)lo.y; hv[2]=(f16)lo.z; hv[3]=(f16)lo.w;
    hv[4]=(f16)hi.x; hv[5]=(f16)hi.y; hv[6]=(f16)hi.z; hv[7]=(f16)hi.w;
    *(f16x8*)(aS + aof[i]) = hv;
  }
}

// L1 compute: one KC=64 chunk, 48 MFMA (6 row-tiles x 4 col-tiles x 2 ks).
__device__ __forceinline__ void mfma96_a(f32x4 (&acc)[6][4], const char* aS,
                                         const char* bS, int w, int g, int l15)
{
  #pragma unroll
  for (int ks = 0; ks < 2; ++ks) {
    f16x8 af[6], bf[4];
    #pragma unroll
    for (int at = 0; at < 6; ++at) {
      const int rr = at * 16 + l15;
      const int p  = (ks * 4 + g) ^ (rr & 7);
      af[at] = *(const f16x8*)(aS + rr * 128 + p * 16);
    }
    #pragma unroll
    for (int bt = 0; bt < 4; ++bt) {
      const int nn = w * 64 + bt * 16 + l15;
      const int p  = (ks * 4 + g) ^ (nn & 7);
      bf[bt] = *(const f16x8*)(bS + nn * 128 + p * 16);
    }
    #pragma unroll
    for (int at = 0; at < 6; ++at)
      #pragma unroll
      for (int bt = 0; bt < 4; ++bt)
        acc[at][bt] = __builtin_amdgcn_mfma_f32_16x16x32_f16(af[at], bf[bt], acc[at][bt], 0, 0, 0);
  }
}

// Hidden compute: one KC=32 chunk, 24 MFMA.
__device__ __forceinline__ void mfma32_h(f32x4 (&acc)[6][4], const char* hL, int c,
                                         const char* wS, int w, int g, int l15)
{
  f16x8 af[6], bf[4];
  #pragma unroll
  for (int at = 0; at < 6; ++at) {
    const int rr = at * 16 + l15;
    af[at] = *(const f16x8*)(hL + ((rr * 512 + c * 64 + g * 16) ^ ((rr & 7) << 4)));
  }
  #pragma unroll
  for (int bt = 0; bt < 4; ++bt) {
    const int nn = w * 64 + bt * 16 + l15;
    bf[bt] = *(const f16x8*)(wS + nn * 64 + ((g ^ ((nn >> 1) & 3)) * 16));
  }
  #pragma unroll
  for (int at = 0; at < 6; ++at)
    #pragma unroll
    for (int bt = 0; bt < 4; ++bt)
      acc[at][bt] = __builtin_amdgcn_mfma_f32_16x16x32_f16(af[at], bf[bt], acc[at][bt], 0, 0, 0);
}

__device__ __forceinline__ void silu_store(f32x4 (&acc)[6][4],
                                           const float* __restrict__ bias,
                                           char* hL, int w, int lane)
{
  const int g = lane >> 4, l15 = lane & 15;
  #pragma unroll
  for (int bt = 0; bt < 4; ++bt) {
    const int col = w * 64 + bt * 16 + l15;
    const float b = bias[col];
    #pragma unroll
    for (int at = 0; at < 6; ++at) {
      #pragma unroll
      for (int j = 0; j < 4; ++j) {
        const int row = at * 16 + g * 4 + j;   // m89-verified C/D mapping
        float x = acc[at][bt][j] + b;
        x = x * __builtin_amdgcn_rcpf(1.f + __expf(-x));
        *(f16*)(hL + (((row * HID + col) * 2) ^ ((row & 7) << 4))) = (f16)x;
      }
    }
  }
}

// aS quad-buffer select (12 KB each)
#define ASB(c) (arena + (((c) & 3) * 12288))

// L1 phase c: VM forces own gll(c); compute; lgkm retires own ds_reads (WAR
// gate for single-bS overwrite); then PINNED issue groups: gll W1(c+1) ->
// feat stage (c+2) -> pa loads (c+4), each fenced by sched_barrier(0) so
// the manual vmcnt ledger matches the emitted order. Barrier on odd phases.
#define L1_STEP(c, PAset, VMN, DOG, DOF, DOPA, DOBAR)              \
  do {                                                             \
    WAIT_VM(VMN); SCHED0();                                        \
    mfma96_a(acc, ASB(c), bS, w, g, l15);                          \
    WAIT_LGKM(); SCHED0();                                         \
    if (DOG)  { stage_w64(bS, w1s, (c) + 1, w, lane); SCHED0(); }  \
    if (DOF)  { stage_feat96(ASB((c) + 2), PAset, aof); SCHED0(); }\
    if (DOPA) { load_pa96(PAset, agp, (c) + 4); SCHED0(); }        \
    if (DOBAR) { WAIT_LGKM(); BARRIER(); }                         \
  } while (0)

// Hidden step: VM(4) readies chunk c, compute, retire own reads, stage
// chunk cs into the buffer just freed (wave-private, pinned). Barrier-free.
#define HID_ST(c, WH, wsrc, cs)                                  \
  do {                                                           \
    WAIT_VM(4); SCHED0();                                        \
    mfma32_h(acc, hL, c, WH, w, g, l15);                         \
    WAIT_LGKM(); SCHED0();                                       \
    stage_w32(WH, wsrc, cs, w, lane); SCHED0();                  \
  } while (0)

__global__ __launch_bounds__(256, 2) void mlp_fused_kernel(
    const float* __restrict__ feats,
    const float* __restrict__ b1g,
    const float* __restrict__ b2g,
    const float* __restrict__ b3g,
    const float* __restrict__ w4g,
    const float* __restrict__ b4g,
    const int*   __restrict__ sidxg,
    const f16*   __restrict__ w1t,
    const f16*   __restrict__ w2t,
    const f16*   __restrict__ w3t,
    float*       __restrict__ outg)
{
  __shared__ char arena[80 * 1024];
  char* bS  = arena + 48 * 1024;     // L1 weights: single 32 KB (wave-private)
  char* hL  = arena;                 // hidden: h [96][256] fp16, 48 KB overlay
  char* wH0 = arena + 48 * 1024;     // hidden weights: 2 x 16 KB (over dead bS)
  char* wH1 = arena + 64 * 1024;

  const int s    = blockIdx.y;
  const int row0 = blockIdx.x * TM;
  const int t    = threadIdx.x;
  const int lane = t & 63;
  const int w    = t >> 6;           // 0..3; wave w owns output cols w*64..+63
  const int g    = lane >> 4;
  const int l15  = lane & 15;

  const float* fbase = feats + (size_t)s * NPER * NF;
  const char*  w1s   = (const char*)(w1t + (size_t)s * HID * NF);
  const char*  w2s   = (const char*)(w2t + (size_t)s * HID * HID);
  const char*  w3s   = (const char*)(w3t + (size_t)s * HID * HID);

  // Per-thread A-staging geometry: 3 units, rows (t+256i)>>3, slot t&7.
  const int sl = t & 7;
  const float* agp[3];
  u32 aof[3];
  #pragma unroll
  for (int i = 0; i < 3; ++i) {
    const int rw = (t + 256 * i) >> 3;          // 0..95
    int rg = row0 + rw; if (rg > NPER - 1) rg = NPER - 1;
    agp[i] = fbase + (size_t)rg * NF + sl * 8;
    aof[i] = (u32)(rw * 128 + ((sl ^ (rw & 7)) << 4));
  }

  f32x4 acc[6][4];

  // ===== L1 prologue (pinned order): pf0,pf1,G(0),paA,paB; stage A0,A1 =====
  float4 pf0[6], pf1[6], paA[6], paB[6];
  load_pa96(pf0, agp, 0);  SCHED0();
  load_pa96(pf1, agp, 1);  SCHED0();
  stage_w64(bS, w1s, 0, w, lane);  SCHED0();
  load_pa96(paA, agp, 2);  SCHED0();
  load_pa96(paB, agp, 3);  SCHED0();
  stage_feat96(ASB(0), pf0, aof);  SCHED0();   // compiler waits pf0 only
  stage_feat96(ASB(1), pf1, aof);  SCHED0();   // compiler waits pf1 only
  zero_acc(acc);
  WAIT_LGKM(); BARRIER();            // publish aS(0), aS(1)

  // ===== L1: 16 phases, KC=64, quad aS, single bS, barrier every 2 =====
  L1_STEP(0,  paA, 12, 1, 1, 1, 0);  // drain gll(0); paA <- pa(4)
  L1_STEP(1,  paB,  6, 1, 1, 1, 1);
  L1_STEP(2,  paA,  6, 1, 1, 1, 0);
  L1_STEP(3,  paB,  6, 1, 1, 1, 1);
  L1_STEP(4,  paA,  6, 1, 1, 1, 0);
  L1_STEP(5,  paB,  6, 1, 1, 1, 1);
  L1_STEP(6,  paA,  6, 1, 1, 1, 0);
  L1_STEP(7,  paB,  6, 1, 1, 1, 1);
  L1_STEP(8,  paA,  6, 1, 1, 1, 0);
  L1_STEP(9,  paB,  6, 1, 1, 1, 1);
  L1_STEP(10, paA,  6, 1, 1, 1, 0);  // paA <- pa(14)
  L1_STEP(11, paB,  6, 1, 1, 1, 1);  // paB <- pa(15), last load
  L1_STEP(12, paA,  6, 1, 1, 0, 0);  // stage aS(14)
  L1_STEP(13, paB,  0, 1, 1, 0, 1);  // stage aS(15); barrier publishes it
  L1_STEP(14, paA,  0, 1, 0, 0, 0);  // gll(15) only
  { // phase 15: last chunk; block-wide barrier ends all aS/bS reads
    WAIT_VM(0); SCHED0();
    mfma96_a(acc, ASB(15), bS, w, g, l15);
    WAIT_LGKM(); BARRIER();
  }

  // ===== L1 -> L2: wH pipeline over dead bS; h over dead aS =====
  stage_w32(wH0, w2s, 0, w, lane);  SCHED0();
  stage_w32(wH1, w2s, 1, w, lane);  SCHED0();
  silu_store(acc, b1g + s * HID, hL, w, lane);
  zero_acc(acc);
  WAIT_LGKM(); BARRIER();            // hL published

  // ===== Layer 2: 8 chunks, KC=32, barrier-free, 2-buf wH, VM(4) =====
  HID_ST(0, wH0, w2s, 2);
  HID_ST(1, wH1, w2s, 3);
  HID_ST(2, wH0, w2s, 4);
  HID_ST(3, wH1, w2s, 5);
  HID_ST(4, wH0, w2s, 6);
  HID_ST(5, wH1, w2s, 7);
  HID_ST(6, wH0, w3s, 0);            // cross into W3 prefetch
  HID_ST(7, wH1, w3s, 1);
  BARRIER();                         // all waves done reading hL
  silu_store(acc, b2g + s * HID, hL, w, lane);
  zero_acc(acc);
  WAIT_LGKM(); BARRIER();            // hL published

  // ===== Layer 3: 8 chunks; wH0=w3(0), wH1=w3(1) already in flight =====
  HID_ST(0, wH0, w3s, 2);
  HID_ST(1, wH1, w3s, 3);
  HID_ST(2, wH0, w3s, 4);
  HID_ST(3, wH1, w3s, 5);
  HID_ST(4, wH0, w3s, 6);
  HID_ST(5, wH1, w3s, 7);
  { WAIT_VM(4); SCHED0(); mfma32_h(acc, hL, 6, wH0, w, g, l15); }
  { WAIT_VM(0); SCHED0(); mfma32_h(acc, hL, 7, wH1, w, g, l15); }
  BARRIER();
  silu_store(acc, b3g + s * HID, hL, w, lane);
  WAIT_LGKM(); BARRIER();

  // ===== Layer 4: e = h @ W4 + b4; segment-sum via atomicAdd =====
  {
    const int row = t >> 1;          // threads 0..191 -> rows 0..95
    const int q   = t & 1;
    if (row < TM) {
      const int grL = row0 + row;
      const float* w4 = w4g + s * HID;
      float sum = 0.f;
      #pragma unroll
      for (int j8 = 0; j8 < 128; j8 += 8) {
        const int k = q * 128 + j8;
        f16x8 hv = *(const f16x8*)(hL + (((row * HID + k) * 2) ^ ((row & 7) << 4)));
        float4 wa = *(const float4*)(w4 + k);
        float4 wb = *(const float4*)(w4 + k + 4);
        sum += (float)hv[0] * wa.x + (float)hv[1] * wa.y + (float)hv[2] * wa.z + (float)hv[3] * wa.w
             + (float)hv[4] * wb.x + (float)hv[5] * wb.y + (float)hv[6] * wb.z + (float)hv[7] * wb.w;
      }
      sum += __shfl_xor(sum, 1);
      if (q == 0 && grL < NPER) {
        atomicAdd(&outg[sidxg[s * NPER + grL]], sum + b4g[s]);
      }
    }
  }
}

// ---------------------------------------------------------------------------
extern "C" void kernel_launch(void* const* d_in, const int* in_sizes, int n_in,
                              void* d_out, int out_size, void* d_ws, size_t ws_size,
                              hipStream_t stream)
{
  const float* feats = (const float*)d_in[0];
  const float* W1    = (const float*)d_in[1];
  const float* b1    = (const float*)d_in[2];
  const float* W2    = (const float*)d_in[3];
  const float* b2    = (const float*)d_in[4];
  const float* W3    = (const float*)d_in[5];
  const float* b3    = (const float*)d_in[6];
  const float* W4    = (const float*)d_in[7];
  const float* b4    = (const float*)d_in[8];
  const int*   sidx  = (const int*)d_in[9];
  float* out = (float*)d_out;

  f16* w1t = (f16*)d_ws;                              // [S][256][1024] fp16
  f16* w2t = w1t + (size_t)S_ * HID * NF;             // [S][256][256]  fp16
  f16* w3t = w2t + (size_t)S_ * HID * HID;            // [S][256][256]  fp16

  hipMemsetAsync(d_out, 0, NSTRUCT * sizeof(float), stream);
  transpose_all_kernel<<<dim3(16, 4, 12), 256, 0, stream>>>(W1, W2, W3, w1t, w2t, w3t);
  mlp_fused_kernel<<<dim3((NPER + TM - 1) / TM, S_), 256, 0, stream>>>(
      feats, b1, b2, b3, W4, b4, sidx, w1t, w2t, w3t, out);
}

// Round 13
// 104.484 us; speedup vs baseline: 1.3236x; 1.3236x over previous
//
#include <hip/hip_runtime.h>

typedef _Float16 f16;
typedef __attribute__((ext_vector_type(8))) _Float16 f16x8;
typedef __attribute__((ext_vector_type(4))) float f32x4;
typedef unsigned int u32;

#define S_      4
#define NPER    12500
#define NF      1024
#define HID     256
#define NSTRUCT 500
#define TM      64

#define GLB __attribute__((address_space(1)))
#define AS3 __attribute__((address_space(3)))

#define WAIT_VM(N)  asm volatile("s_waitcnt vmcnt(" #N ")" ::: "memory")
#define WAIT_LGKM() asm volatile("s_waitcnt lgkmcnt(0)" ::: "memory")
#define SCHED0()    __builtin_amdgcn_sched_barrier(0)
#define BARRIER()   do { __builtin_amdgcn_s_barrier(); SCHED0(); } while (0)

// ---------------------------------------------------------------------------
// Fused weight transpose + fp32->fp16 (all 3 layers, 1 launch)
// ---------------------------------------------------------------------------
__global__ __launch_bounds__(256) void transpose_all_kernel(
    const float* __restrict__ W1, const float* __restrict__ W2,
    const float* __restrict__ W3,
    f16* __restrict__ w1t, f16* __restrict__ w2t, f16* __restrict__ w3t)
{
  const int z = blockIdx.z;            // layer*4 + species
  const int layer = z >> 2, sp = z & 3;
  const float* in; f16* out; int K;
  if (layer == 0)      { in = W1; out = w1t; K = NF;  }
  else if (layer == 1) { in = W2; out = w2t; K = HID; }
  else                 { in = W3; out = w3t; K = HID; }
  if (blockIdx.x * 64 >= K) return;

  __shared__ float tile[64][65];
  const float* inp = in + (size_t)sp * K * HID;
  f16* outp = out + (size_t)sp * K * HID;
  const int k0 = blockIdx.x * 64;
  const int n0 = blockIdx.y * 64;
  const int t = threadIdx.x;
  {
    const int lk = t >> 2;
    const int nq = (t & 3) * 16;
    const float* src = inp + (size_t)(k0 + lk) * HID + n0 + nq;
    #pragma unroll
    for (int i = 0; i < 4; ++i) {
      float4 v = *(const float4*)(src + i * 4);
      tile[lk][nq + i * 4 + 0] = v.x;
      tile[lk][nq + i * 4 + 1] = v.y;
      tile[lk][nq + i * 4 + 2] = v.z;
      tile[lk][nq + i * 4 + 3] = v.w;
    }
  }
  __syncthreads();
  {
    const int ln = t >> 2;
    const int kq = (t & 3) * 16;
    f16* dst = outp + (size_t)(n0 + ln) * K + k0 + kq;
    f16x8 a, b;
    #pragma unroll
    for (int j = 0; j < 8; ++j) a[j] = (f16)tile[kq + j][ln];
    #pragma unroll
    for (int j = 0; j < 8; ++j) b[j] = (f16)tile[kq + 8 + j][ln];
    *(f16x8*)dst = a;
    *(f16x8*)(dst + 8) = b;
  }
}

// ---------------------------------------------------------------------------
// Fused MLP R20 = R17 verbatim (session best, 104.0 us verified):
//  - bS wave-private on BOTH sides -> single 32 KB buffer, staged after the
//    wave's own lgkm-drain (no barrier needed for bS).
//  - aS QUAD buffer (4 x 8 KB), stage distance 2: barrier every 2 phases
//    publishes TWO staged A tiles (8 L1 barriers instead of 16).
//  - Steady vmcnt: entering phase c queue = [pa(c+3)4, gll(c)8, pa(c+4)4]
//    -> VM(4) forces gll(c), keeps pa(c+4). pa: 3 sets, load distance 5.
//  - Hidden layers: wS 3-buffer gll rotation + VM(8) (beat reg-B in R16),
//    barrier-free inside layers.
//  - Arena 80 KB, launch_bounds(256,2).
// Session lessons banked: fat-tile x high-occupancy is register-infeasible
// (R15/R18/R19 spills); thin phases break latency cover (R11); manual vmcnt
// requires either scheduler luck or full issue-order pinning (R18 vs R19);
// WRITE_SIZE is the spill canary.
// ---------------------------------------------------------------------------

__device__ __forceinline__ void zero_acc(f32x4 (&acc)[4][4]) {
  #pragma unroll
  for (int a = 0; a < 4; ++a)
    #pragma unroll
    for (int b = 0; b < 4; ++b)
      #pragma unroll
      for (int j = 0; j < 4; ++j) acc[a][b][j] = 0.f;
}

// L1 weights: bS [256 n][8 slots of 16B]; phys slot p at row r holds k-slot
// p^(r&7). Wave w stages rows w*64..+63 -- exactly the rows it alone reads.
__device__ __forceinline__ void stage_w64(char* bS, const char* wbase, int c,
                                          int w, int lane)
{
  #pragma unroll
  for (int i = 0; i < 8; ++i) {
    const int seg  = w * 8 + i;                 // 0..31
    const int rloc = lane >> 3;                 // 0..7
    const int p    = lane & 7;                  // phys 16B slot
    const int row  = seg * 8 + rloc;            // 0..255
    const int slog = p ^ rloc;                  // logical k-slot (row&7 == rloc)
    const char* gp = wbase + (size_t)row * (NF * 2) + (size_t)c * 128 + slog * 16;
    char* lp = bS + seg * 1024;                 // wave-uniform base
    __builtin_amdgcn_global_load_lds((const GLB u32*)gp, (AS3 u32*)lp, 16, 0, 0);
  }
}

// Hidden weights: [256 n][32 k], phys slot = log ^ ((row>>1)&3). Self-staged.
__device__ __forceinline__ void stage_w32(char* wS, const char* wbase, int c,
                                          int w, int lane)
{
  #pragma unroll
  for (int i = 0; i < 4; ++i) {
    const int seg = w * 4 + i;                  // 0..15
    const int row = seg * 16 + (lane >> 2);     // 0..255
    const int kbp = lane & 3;
    const int kb  = kbp ^ ((row >> 1) & 3);
    const char* gp = wbase + (size_t)row * (HID * 2) + c * 64 + kb * 16;
    char* lp = wS + seg * 1024;
    __builtin_amdgcn_global_load_lds((const GLB u32*)gp, (AS3 u32*)lp, 16, 0, 0);
  }
}

__device__ __forceinline__ void load_pa(float4 (&pa)[4], const float* fsrcT, int c)
{
  #pragma unroll
  for (int j = 0; j < 4; ++j)
    pa[j] = *(const float4*)(fsrcT + c * 64 + j * 4);
}

// Features chunk [64 r][64 k] fp32->fp16 into aS (ds_write).
__device__ __forceinline__ void stage_feat64(char* aS, const float4 (&pa)[4], int t)
{
  const int r = t >> 2;
  #pragma unroll
  for (int wr = 0; wr < 2; ++wr) {
    f16x8 hv;
    const float4 lo = pa[wr * 2 + 0], hi = pa[wr * 2 + 1];
    hv[0]=(f16)lo.x; hv[1]=(f16)lo.y; hv[2]=(f16)lo.z; hv[3]=(f16)lo.w;
    hv[4]=(f16)hi.x; hv[5]=(f16)hi.y; hv[6]=(f16)hi.z; hv[7]=(f16)hi.w;
    const int slog = (t & 3) * 2 + wr;
    const int p = slog ^ (r & 7);
    *(f16x8*)(aS + r * 128 + p * 16) = hv;
  }
}

// L1 compute: one KC=64 chunk, 32 MFMA.
__device__ __forceinline__ void mfma64_a(f32x4 (&acc)[4][4], const char* aS,
                                         const char* bS, int w, int g, int l15)
{
  #pragma unroll
  for (int ks = 0; ks < 2; ++ks) {
    f16x8 af[4], bf[4];
    #pragma unroll
    for (int at = 0; at < 4; ++at) {
      const int rr = at * 16 + l15;
      const int p  = (ks * 4 + g) ^ (rr & 7);
      af[at] = *(const f16x8*)(aS + rr * 128 + p * 16);
    }
    #pragma unroll
    for (int bt = 0; bt < 4; ++bt) {
      const int nn = w * 64 + bt * 16 + l15;
      const int p  = (ks * 4 + g) ^ (nn & 7);
      bf[bt] = *(const f16x8*)(bS + nn * 128 + p * 16);
    }
    #pragma unroll
    for (int at = 0; at < 4; ++at)
      #pragma unroll
      for (int bt = 0; bt < 4; ++bt)
        acc[at][bt] = __builtin_amdgcn_mfma_f32_16x16x32_f16(af[at], bf[bt], acc[at][bt], 0, 0, 0);
  }
}

// Hidden compute: one KC=32 chunk, 16 MFMA.
__device__ __forceinline__ void mfma32_h(f32x4 (&acc)[4][4], const char* hL, int c,
                                         const char* wS, int w, int g, int l15)
{
  f16x8 af[4], bf[4];
  #pragma unroll
  for (int at = 0; at < 4; ++at) {
    const int rr = at * 16 + l15;
    af[at] = *(const f16x8*)(hL + ((rr * 512 + c * 64 + g * 16) ^ ((rr & 7) << 4)));
  }
  #pragma unroll
  for (int bt = 0; bt < 4; ++bt) {
    const int nn = w * 64 + bt * 16 + l15;
    bf[bt] = *(const f16x8*)(wS + nn * 64 + ((g ^ ((nn >> 1) & 3)) * 16));
  }
  #pragma unroll
  for (int at = 0; at < 4; ++at)
    #pragma unroll
    for (int bt = 0; bt < 4; ++bt)
      acc[at][bt] = __builtin_amdgcn_mfma_f32_16x16x32_f16(af[at], bf[bt], acc[at][bt], 0, 0, 0);
}

__device__ __forceinline__ void silu_store(f32x4 (&acc)[4][4],
                                           const float* __restrict__ bias,
                                           char* hL, int w, int lane)
{
  const int g = lane >> 4, l15 = lane & 15;
  #pragma unroll
  for (int bt = 0; bt < 4; ++bt) {
    const int col = w * 64 + bt * 16 + l15;
    const float b = bias[col];
    #pragma unroll
    for (int at = 0; at < 4; ++at) {
      #pragma unroll
      for (int j = 0; j < 4; ++j) {
        const int row = at * 16 + g * 4 + j;   // m89-verified C/D mapping
        float x = acc[at][bt][j] + b;
        x = x * __builtin_amdgcn_rcpf(1.f + __expf(-x));
        *(f16*)(hL + (((row * HID + col) * 2) ^ ((row & 7) << 4))) = (f16)x;
      }
    }
  }
}

// aS quad-buffer select (8 KB each)
#define ASB(c) (arena + (((c) & 3) << 13))

// L1 phase c: VM forces own gll(c); compute chunk c; lgkm retires own
// ds_reads (WAR gate for the single-bS overwrite); gll W1(c+1) into own
// slice; stage feat(c+2) into quad slot; refill pa(c+5); barrier only on
// odd phases (publishes the two A tiles staged since the last barrier).
#define L1_STEP(c, PAset, VMN, DOG, DOF, DOPA, DOBAR)            \
  do {                                                           \
    WAIT_VM(VMN); SCHED0();                                      \
    mfma64_a(acc, ASB(c), bS, w, g, l15);                        \
    WAIT_LGKM(); SCHED0();                                       \
    if (DOG)  stage_w64(bS, w1s, (c) + 1, w, lane);              \
    if (DOF)  stage_feat64(ASB((c) + 2), PAset, t);              \
    if (DOPA) load_pa(PAset, fsrcT, (c) + 5);                    \
    if (DOBAR) { WAIT_LGKM(); BARRIER(); }                       \
  } while (0)

// Hidden step: counted wait readies chunk c, compute, drain own reads,
// stage chunk c+3 into the buffer just freed. Barrier-free.
#define HID_ST(c, WSc, wsrc, cs)                                 \
  do {                                                           \
    WAIT_VM(8); SCHED0();                                        \
    mfma32_h(acc, hL, c, WSc, w, g, l15);                        \
    WAIT_LGKM(); SCHED0();                                       \
    stage_w32(WSc, wsrc, cs, w, lane);                           \
  } while (0)

__global__ __launch_bounds__(256, 2) void mlp_fused_kernel(
    const float* __restrict__ feats,
    const float* __restrict__ b1g,
    const float* __restrict__ b2g,
    const float* __restrict__ b3g,
    const float* __restrict__ w4g,
    const float* __restrict__ b4g,
    const int*   __restrict__ sidxg,
    const f16*   __restrict__ w1t,
    const f16*   __restrict__ w2t,
    const f16*   __restrict__ w3t,
    float*       __restrict__ outg)
{
  __shared__ char arena[80 * 1024];
  char* bS  = arena + 32 * 1024;     // L1 weights: single 32 KB (wave-private)
  char* hL  = arena;                 // hidden: h [64][256] fp16, 32 KB overlay
  char* wH0 = arena + 64 * 1024;     // hidden weights rotation: 3 x 16 KB
  char* wH1 = arena + 32 * 1024;     //   (wH0 free at ph15; wH1/wH2 over bS)
  char* wH2 = arena + 48 * 1024;

  const int s    = blockIdx.y;
  const int row0 = blockIdx.x * TM;
  const int t    = threadIdx.x;
  const int lane = t & 63;
  const int w    = t >> 6;           // 0..3; wave w owns output cols w*64..+63
  const int g    = lane >> 4;
  const int l15  = lane & 15;

  const int gr   = row0 + (t >> 2);
  const bool valid = gr < NPER;
  const int grc  = valid ? gr : (NPER - 1);
  const float* fsrcT = feats + ((size_t)s * NPER + grc) * NF + (t & 3) * 16;
  const char*  w1s   = (const char*)(w1t + (size_t)s * HID * NF);
  const char*  w2s   = (const char*)(w2t + (size_t)s * HID * HID);
  const char*  w3s   = (const char*)(w3t + (size_t)s * HID * HID);

  f32x4 acc[4][4];
  zero_acc(acc);

  // ===== L1 prologue: aS(0),aS(1) staged; gll(0); pa(2..4) in 3 sets =====
  float4 pf0[4], pf1[4], paA[4], paB[4], paC[4];
  load_pa(pf0, fsrcT, 0);
  load_pa(pf1, fsrcT, 1);
  stage_w64(bS, w1s, 0, w, lane);
  load_pa(paA, fsrcT, 2);
  load_pa(paB, fsrcT, 3);
  load_pa(paC, fsrcT, 4);
  stage_feat64(ASB(0), pf0, t);      // compiler waits pf0 only (keeps gll/pa)
  stage_feat64(ASB(1), pf1, t);      // compiler waits pf1 only
  WAIT_LGKM(); BARRIER();            // publish aS(0), aS(1)

  // ===== L1: 16 phases, KC=64, quad aS, single bS, barrier every 2 =====
  // Set map: phase c consumes pa(c+2) from set[c%3], reloads it <- pa(c+5).
  L1_STEP(0,  paA, 12, 1, 1, 1, 0);
  L1_STEP(1,  paB,  4, 1, 1, 1, 1);
  L1_STEP(2,  paC,  4, 1, 1, 1, 0);
  L1_STEP(3,  paA,  4, 1, 1, 1, 1);
  L1_STEP(4,  paB,  4, 1, 1, 1, 0);
  L1_STEP(5,  paC,  4, 1, 1, 1, 1);
  L1_STEP(6,  paA,  4, 1, 1, 1, 0);
  L1_STEP(7,  paB,  4, 1, 1, 1, 1);
  L1_STEP(8,  paC,  4, 1, 1, 1, 0);
  L1_STEP(9,  paA,  4, 1, 1, 1, 1);
  L1_STEP(10, paB,  4, 1, 1, 1, 0);  // loads pa(15) -> paB (last pa)
  L1_STEP(11, paC,  4, 1, 1, 0, 1);  // stage aS(13)
  L1_STEP(12, paA,  0, 1, 1, 0, 0);  // stage aS(14) from pa(14)=paA
  L1_STEP(13, paB,  0, 1, 1, 0, 1);  // stage aS(15) from pa(15)=paB
  L1_STEP(14, paC,  0, 1, 0, 0, 0);  // gll(15); no more feat staging
  { // phase 15: last chunk; early-stage W2 chunk0 into wH0 (free region)
    WAIT_VM(0); SCHED0();
    mfma64_a(acc, ASB(15), bS, w, g, l15);
    WAIT_LGKM(); SCHED0();
    stage_w32(wH0, w2s, 0, w, lane);
    WAIT_LGKM(); BARRIER();          // all aS/bS reads done block-wide
  }

  // ===== L1 -> L2: h over dead aS; fill wS pipeline over dead bS =====
  silu_store(acc, b1g + s * HID, hL, w, lane);
  zero_acc(acc);
  stage_w32(wH1, w2s, 1, w, lane);
  stage_w32(wH2, w2s, 2, w, lane);
  WAIT_LGKM(); BARRIER();            // hL published

  // ===== Layer 2: 8 chunks, KC=32, barrier-free, 3-buf wS, VM(8) =====
  HID_ST(0, wH0, w2s, 3);
  HID_ST(1, wH1, w2s, 4);
  HID_ST(2, wH2, w2s, 5);
  HID_ST(3, wH0, w2s, 6);
  HID_ST(4, wH1, w2s, 7);
  HID_ST(5, wH2, w3s, 0);            // cross into W3 prefetch
  HID_ST(6, wH0, w3s, 1);
  HID_ST(7, wH1, w3s, 2);
  BARRIER();                         // all waves done reading hL
  silu_store(acc, b2g + s * HID, hL, w, lane);
  zero_acc(acc);
  WAIT_LGKM(); BARRIER();            // hL published

  // ===== Layer 3: 8 chunks; in flight: 0(wH2),1(wH0),2(wH1) =====
  HID_ST(0, wH2, w3s, 3);
  HID_ST(1, wH0, w3s, 4);
  HID_ST(2, wH1, w3s, 5);
  HID_ST(3, wH2, w3s, 6);
  HID_ST(4, wH0, w3s, 7);
  { WAIT_VM(8); SCHED0(); mfma32_h(acc, hL, 5, wH1, w, g, l15); }
  { WAIT_VM(4); SCHED0(); mfma32_h(acc, hL, 6, wH2, w, g, l15); }
  { WAIT_VM(0); SCHED0(); mfma32_h(acc, hL, 7, wH0, w, g, l15); }
  BARRIER();
  silu_store(acc, b3g + s * HID, hL, w, lane);
  WAIT_LGKM(); BARRIER();

  // ===== Layer 4: e = h @ W4 + b4; segment-sum via atomicAdd =====
  {
    const int row = t >> 2;
    const int q   = t & 3;
    const float* w4 = w4g + s * HID;
    float sum = 0.f;
    #pragma unroll
    for (int j8 = 0; j8 < 64; j8 += 8) {
      const int k = q * 64 + j8;
      f16x8 hv = *(const f16x8*)(hL + (((row * HID + k) * 2) ^ ((row & 7) << 4)));
      float4 wa = *(const float4*)(w4 + k);
      float4 wb = *(const float4*)(w4 + k + 4);
      sum += (float)hv[0] * wa.x + (float)hv[1] * wa.y + (float)hv[2] * wa.z + (float)hv[3] * wa.w
           + (float)hv[4] * wb.x + (float)hv[5] * wb.y + (float)hv[6] * wb.z + (float)hv[7] * wb.w;
    }
    sum += __shfl_xor(sum, 1);
    sum += __shfl_xor(sum, 2);
    if (q == 0 && valid) {
      atomicAdd(&outg[sidxg[s * NPER + gr]], sum + b4g[s]);
    }
  }
}

// ---------------------------------------------------------------------------
extern "C" void kernel_launch(void* const* d_in, const int* in_sizes, int n_in,
                              void* d_out, int out_size, void* d_ws, size_t ws_size,
                              hipStream_t stream)
{
  const float* feats = (const float*)d_in[0];
  const float* W1    = (const float*)d_in[1];
  const float* b1    = (const float*)d_in[2];
  const float* W2    = (const float*)d_in[3];
  const float* b2    = (const float*)d_in[4];
  const float* W3    = (const float*)d_in[5];
  const float* b3    = (const float*)d_in[6];
  const float* W4    = (const float*)d_in[7];
  const float* b4    = (const float*)d_in[8];
  const int*   sidx  = (const int*)d_in[9];
  float* out = (float*)d_out;

  f16* w1t = (f16*)d_ws;                              // [S][256][1024] fp16
  f16* w2t = w1t + (size_t)S_ * HID * NF;             // [S][256][256]  fp16
  f16* w3t = w2t + (size_t)S_ * HID * HID;            // [S][256][256]  fp16

  hipMemsetAsync(d_out, 0, NSTRUCT * sizeof(float), stream);
  transpose_all_kernel<<<dim3(16, 4, 12), 256, 0, stream>>>(W1, W2, W3, w1t, w2t, w3t);
  mlp_fused_kernel<<<dim3((NPER + TM - 1) / TM, S_), 256, 0, stream>>>(
      feats, b1, b2, b3, W4, b4, sidx, w1t, w2t, w3t, out);
}

// Round 14
// 93.308 us; speedup vs baseline: 1.4822x; 1.1198x over previous
//
#include <hip/hip_runtime.h>

typedef _Float16 f16;
typedef __attribute__((ext_vector_type(8))) _Float16 f16x8;
typedef __attribute__((ext_vector_type(4))) float f32x4;
typedef unsigned int u32;

#define S_      4
#define NPER    12500
#define NF      1024
#define HID     256
#define NSTRUCT 500
#define TM      64

#define GLB __attribute__((address_space(1)))
#define AS3 __attribute__((address_space(3)))

#define WAIT_VM(N)  asm volatile("s_waitcnt vmcnt(" #N ")" ::: "memory")
#define WAIT_LGKM() asm volatile("s_waitcnt lgkmcnt(0)" ::: "memory")
#define SCHED0()    __builtin_amdgcn_sched_barrier(0)
#define BARRIER()   do { __builtin_amdgcn_s_barrier(); SCHED0(); } while (0)

// ---------------------------------------------------------------------------
// Fused weight transpose + fp32->fp16 (all 3 layers, 1 launch)
// ---------------------------------------------------------------------------
__global__ __launch_bounds__(256) void transpose_all_kernel(
    const float* __restrict__ W1, const float* __restrict__ W2,
    const float* __restrict__ W3,
    f16* __restrict__ w1t, f16* __restrict__ w2t, f16* __restrict__ w3t)
{
  const int z = blockIdx.z;            // layer*4 + species
  const int layer = z >> 2, sp = z & 3;
  const float* in; f16* out; int K;
  if (layer == 0)      { in = W1; out = w1t; K = NF;  }
  else if (layer == 1) { in = W2; out = w2t; K = HID; }
  else                 { in = W3; out = w3t; K = HID; }
  if (blockIdx.x * 64 >= K) return;

  __shared__ float tile[64][65];
  const float* inp = in + (size_t)sp * K * HID;
  f16* outp = out + (size_t)sp * K * HID;
  const int k0 = blockIdx.x * 64;
  const int n0 = blockIdx.y * 64;
  const int t = threadIdx.x;
  {
    const int lk = t >> 2;
    const int nq = (t & 3) * 16;
    const float* src = inp + (size_t)(k0 + lk) * HID + n0 + nq;
    #pragma unroll
    for (int i = 0; i < 4; ++i) {
      float4 v = *(const float4*)(src + i * 4);
      tile[lk][nq + i * 4 + 0] = v.x;
      tile[lk][nq + i * 4 + 1] = v.y;
      tile[lk][nq + i * 4 + 2] = v.z;
      tile[lk][nq + i * 4 + 3] = v.w;
    }
  }
  __syncthreads();
  {
    const int ln = t >> 2;
    const int kq = (t & 3) * 16;
    f16* dst = outp + (size_t)(n0 + ln) * K + k0 + kq;
    f16x8 a, b;
    #pragma unroll
    for (int j = 0; j < 8; ++j) a[j] = (f16)tile[kq + j][ln];
    #pragma unroll
    for (int j = 0; j < 8; ++j) b[j] = (f16)tile[kq + 8 + j][ln];
    *(f16x8*)dst = a;
    *(f16x8*)(dst + 8) = b;
  }
}

// ---------------------------------------------------------------------------
// Fused MLP R22 = R17/R20 (verified best, 104.0/104.5) + fused L4 epilogue:
//  - Layer 3's silu + W4 dot are computed entirely in registers (no hL
//    round-trip): each lane folds silu(acc+b3)*w4 over its 4 cols, 4 rounds
//    of shfl_xor (bits 0-3, within the 16-lane g-group) reduce over l15,
//    l15==0 lanes deposit per-wave row sums into 1 KB of dead LDS, one
//    64-thread pass does the cross-wave sum + atomicAdd.
//  - b3/w4 loads issued AFTER the final hidden barrier so the hidden-layer
//    VM(N) ledgers are untouched (R18 lesson: unpinned VMEM breaks counts).
//  - Everything else is R20 verbatim (quad-aS barrier-every-2, single
//    wave-private bS, wS 3-buffer hidden, 80 KB arena, (256,2)).
// ---------------------------------------------------------------------------

__device__ __forceinline__ void zero_acc(f32x4 (&acc)[4][4]) {
  #pragma unroll
  for (int a = 0; a < 4; ++a)
    #pragma unroll
    for (int b = 0; b < 4; ++b)
      #pragma unroll
      for (int j = 0; j < 4; ++j) acc[a][b][j] = 0.f;
}

// L1 weights: bS [256 n][8 slots of 16B]; phys slot p at row r holds k-slot
// p^(r&7). Wave w stages rows w*64..+63 -- exactly the rows it alone reads.
__device__ __forceinline__ void stage_w64(char* bS, const char* wbase, int c,
                                          int w, int lane)
{
  #pragma unroll
  for (int i = 0; i < 8; ++i) {
    const int seg  = w * 8 + i;                 // 0..31
    const int rloc = lane >> 3;                 // 0..7
    const int p    = lane & 7;                  // phys 16B slot
    const int row  = seg * 8 + rloc;            // 0..255
    const int slog = p ^ rloc;                  // logical k-slot (row&7 == rloc)
    const char* gp = wbase + (size_t)row * (NF * 2) + (size_t)c * 128 + slog * 16;
    char* lp = bS + seg * 1024;                 // wave-uniform base
    __builtin_amdgcn_global_load_lds((const GLB u32*)gp, (AS3 u32*)lp, 16, 0, 0);
  }
}

// Hidden weights: [256 n][32 k], phys slot = log ^ ((row>>1)&3). Self-staged.
__device__ __forceinline__ void stage_w32(char* wS, const char* wbase, int c,
                                          int w, int lane)
{
  #pragma unroll
  for (int i = 0; i < 4; ++i) {
    const int seg = w * 4 + i;                  // 0..15
    const int row = seg * 16 + (lane >> 2);     // 0..255
    const int kbp = lane & 3;
    const int kb  = kbp ^ ((row >> 1) & 3);
    const char* gp = wbase + (size_t)row * (HID * 2) + c * 64 + kb * 16;
    char* lp = wS + seg * 1024;
    __builtin_amdgcn_global_load_lds((const GLB u32*)gp, (AS3 u32*)lp, 16, 0, 0);
  }
}

__device__ __forceinline__ void load_pa(float4 (&pa)[4], const float* fsrcT, int c)
{
  #pragma unroll
  for (int j = 0; j < 4; ++j)
    pa[j] = *(const float4*)(fsrcT + c * 64 + j * 4);
}

// Features chunk [64 r][64 k] fp32->fp16 into aS (ds_write).
__device__ __forceinline__ void stage_feat64(char* aS, const float4 (&pa)[4], int t)
{
  const int r = t >> 2;
  #pragma unroll
  for (int wr = 0; wr < 2; ++wr) {
    f16x8 hv;
    const float4 lo = pa[wr * 2 + 0], hi = pa[wr * 2 + 1];
    hv[0]=(f16)lo.x; hv[1]=(f16)lo.y; hv[2]=(f16)lo.z; hv[3]=(f16)lo.w;
    hv[4]=(f16)hi.x; hv[5]=(f16)hi.y; hv[6]=(f16)hi.z; hv[7]=(f16)hi.w;
    const int slog = (t & 3) * 2 + wr;
    const int p = slog ^ (r & 7);
    *(f16x8*)(aS + r * 128 + p * 16) = hv;
  }
}

// L1 compute: one KC=64 chunk, 32 MFMA.
__device__ __forceinline__ void mfma64_a(f32x4 (&acc)[4][4], const char* aS,
                                         const char* bS, int w, int g, int l15)
{
  #pragma unroll
  for (int ks = 0; ks < 2; ++ks) {
    f16x8 af[4], bf[4];
    #pragma unroll
    for (int at = 0; at < 4; ++at) {
      const int rr = at * 16 + l15;
      const int p  = (ks * 4 + g) ^ (rr & 7);
      af[at] = *(const f16x8*)(aS + rr * 128 + p * 16);
    }
    #pragma unroll
    for (int bt = 0; bt < 4; ++bt) {
      const int nn = w * 64 + bt * 16 + l15;
      const int p  = (ks * 4 + g) ^ (nn & 7);
      bf[bt] = *(const f16x8*)(bS + nn * 128 + p * 16);
    }
    #pragma unroll
    for (int at = 0; at < 4; ++at)
      #pragma unroll
      for (int bt = 0; bt < 4; ++bt)
        acc[at][bt] = __builtin_amdgcn_mfma_f32_16x16x32_f16(af[at], bf[bt], acc[at][bt], 0, 0, 0);
  }
}

// Hidden compute: one KC=32 chunk, 16 MFMA.
__device__ __forceinline__ void mfma32_h(f32x4 (&acc)[4][4], const char* hL, int c,
                                         const char* wS, int w, int g, int l15)
{
  f16x8 af[4], bf[4];
  #pragma unroll
  for (int at = 0; at < 4; ++at) {
    const int rr = at * 16 + l15;
    af[at] = *(const f16x8*)(hL + ((rr * 512 + c * 64 + g * 16) ^ ((rr & 7) << 4)));
  }
  #pragma unroll
  for (int bt = 0; bt < 4; ++bt) {
    const int nn = w * 64 + bt * 16 + l15;
    bf[bt] = *(const f16x8*)(wS + nn * 64 + ((g ^ ((nn >> 1) & 3)) * 16));
  }
  #pragma unroll
  for (int at = 0; at < 4; ++at)
    #pragma unroll
    for (int bt = 0; bt < 4; ++bt)
      acc[at][bt] = __builtin_amdgcn_mfma_f32_16x16x32_f16(af[at], bf[bt], acc[at][bt], 0, 0, 0);
}

__device__ __forceinline__ void silu_store(f32x4 (&acc)[4][4],
                                           const float* __restrict__ bias,
                                           char* hL, int w, int lane)
{
  const int g = lane >> 4, l15 = lane & 15;
  #pragma unroll
  for (int bt = 0; bt < 4; ++bt) {
    const int col = w * 64 + bt * 16 + l15;
    const float b = bias[col];
    #pragma unroll
    for (int at = 0; at < 4; ++at) {
      #pragma unroll
      for (int j = 0; j < 4; ++j) {
        const int row = at * 16 + g * 4 + j;   // m89-verified C/D mapping
        float x = acc[at][bt][j] + b;
        x = x * __builtin_amdgcn_rcpf(1.f + __expf(-x));
        *(f16*)(hL + (((row * HID + col) * 2) ^ ((row & 7) << 4))) = (f16)x;
      }
    }
  }
}

// aS quad-buffer select (8 KB each)
#define ASB(c) (arena + (((c) & 3) << 13))

// L1 phase c: VM forces own gll(c); compute chunk c; lgkm retires own
// ds_reads (WAR gate for the single-bS overwrite); gll W1(c+1) into own
// slice; stage feat(c+2) into quad slot; refill pa(c+5); barrier only on
// odd phases (publishes the two A tiles staged since the last barrier).
#define L1_STEP(c, PAset, VMN, DOG, DOF, DOPA, DOBAR)            \
  do {                                                           \
    WAIT_VM(VMN); SCHED0();                                      \
    mfma64_a(acc, ASB(c), bS, w, g, l15);                        \
    WAIT_LGKM(); SCHED0();                                       \
    if (DOG)  stage_w64(bS, w1s, (c) + 1, w, lane);              \
    if (DOF)  stage_feat64(ASB((c) + 2), PAset, t);              \
    if (DOPA) load_pa(PAset, fsrcT, (c) + 5);                    \
    if (DOBAR) { WAIT_LGKM(); BARRIER(); }                       \
  } while (0)

// Hidden step: counted wait readies chunk c, compute, drain own reads,
// stage chunk c+3 into the buffer just freed. Barrier-free.
#define HID_ST(c, WSc, wsrc, cs)                                 \
  do {                                                           \
    WAIT_VM(8); SCHED0();                                        \
    mfma32_h(acc, hL, c, WSc, w, g, l15);                        \
    WAIT_LGKM(); SCHED0();                                       \
    stage_w32(WSc, wsrc, cs, w, lane);                           \
  } while (0)

__global__ __launch_bounds__(256, 2) void mlp_fused_kernel(
    const float* __restrict__ feats,
    const float* __restrict__ b1g,
    const float* __restrict__ b2g,
    const float* __restrict__ b3g,
    const float* __restrict__ w4g,
    const float* __restrict__ b4g,
    const int*   __restrict__ sidxg,
    const f16*   __restrict__ w1t,
    const f16*   __restrict__ w2t,
    const f16*   __restrict__ w3t,
    float*       __restrict__ outg)
{
  __shared__ char arena[80 * 1024];
  char* bS  = arena + 32 * 1024;     // L1 weights: single 32 KB (wave-private)
  char* hL  = arena;                 // hidden: h [64][256] fp16, 32 KB overlay
  char* wH0 = arena + 64 * 1024;     // hidden weights rotation: 3 x 16 KB
  char* wH1 = arena + 32 * 1024;     //   (wH0 free at ph15; wH1/wH2 over bS)
  char* wH2 = arena + 48 * 1024;

  const int s    = blockIdx.y;
  const int row0 = blockIdx.x * TM;
  const int t    = threadIdx.x;
  const int lane = t & 63;
  const int w    = t >> 6;           // 0..3; wave w owns output cols w*64..+63
  const int g    = lane >> 4;
  const int l15  = lane & 15;

  const int gr   = row0 + (t >> 2);
  const bool valid = gr < NPER;
  const int grc  = valid ? gr : (NPER - 1);
  const float* fsrcT = feats + ((size_t)s * NPER + grc) * NF + (t & 3) * 16;
  const char*  w1s   = (const char*)(w1t + (size_t)s * HID * NF);
  const char*  w2s   = (const char*)(w2t + (size_t)s * HID * HID);
  const char*  w3s   = (const char*)(w3t + (size_t)s * HID * HID);

  f32x4 acc[4][4];
  zero_acc(acc);

  // ===== L1 prologue: aS(0),aS(1) staged; gll(0); pa(2..4) in 3 sets =====
  float4 pf0[4], pf1[4], paA[4], paB[4], paC[4];
  load_pa(pf0, fsrcT, 0);
  load_pa(pf1, fsrcT, 1);
  stage_w64(bS, w1s, 0, w, lane);
  load_pa(paA, fsrcT, 2);
  load_pa(paB, fsrcT, 3);
  load_pa(paC, fsrcT, 4);
  stage_feat64(ASB(0), pf0, t);      // compiler waits pf0 only (keeps gll/pa)
  stage_feat64(ASB(1), pf1, t);      // compiler waits pf1 only
  WAIT_LGKM(); BARRIER();            // publish aS(0), aS(1)

  // ===== L1: 16 phases, KC=64, quad aS, single bS, barrier every 2 =====
  // Set map: phase c consumes pa(c+2) from set[c%3], reloads it <- pa(c+5).
  L1_STEP(0,  paA, 12, 1, 1, 1, 0);
  L1_STEP(1,  paB,  4, 1, 1, 1, 1);
  L1_STEP(2,  paC,  4, 1, 1, 1, 0);
  L1_STEP(3,  paA,  4, 1, 1, 1, 1);
  L1_STEP(4,  paB,  4, 1, 1, 1, 0);
  L1_STEP(5,  paC,  4, 1, 1, 1, 1);
  L1_STEP(6,  paA,  4, 1, 1, 1, 0);
  L1_STEP(7,  paB,  4, 1, 1, 1, 1);
  L1_STEP(8,  paC,  4, 1, 1, 1, 0);
  L1_STEP(9,  paA,  4, 1, 1, 1, 1);
  L1_STEP(10, paB,  4, 1, 1, 1, 0);  // loads pa(15) -> paB (last pa)
  L1_STEP(11, paC,  4, 1, 1, 0, 1);  // stage aS(13)
  L1_STEP(12, paA,  0, 1, 1, 0, 0);  // stage aS(14) from pa(14)=paA
  L1_STEP(13, paB,  0, 1, 1, 0, 1);  // stage aS(15) from pa(15)=paB
  L1_STEP(14, paC,  0, 1, 0, 0, 0);  // gll(15); no more feat staging
  { // phase 15: last chunk; early-stage W2 chunk0 into wH0 (free region)
    WAIT_VM(0); SCHED0();
    mfma64_a(acc, ASB(15), bS, w, g, l15);
    WAIT_LGKM(); SCHED0();
    stage_w32(wH0, w2s, 0, w, lane);
    WAIT_LGKM(); BARRIER();          // all aS/bS reads done block-wide
  }

  // ===== L1 -> L2: h over dead aS; fill wS pipeline over dead bS =====
  silu_store(acc, b1g + s * HID, hL, w, lane);
  zero_acc(acc);
  stage_w32(wH1, w2s, 1, w, lane);
  stage_w32(wH2, w2s, 2, w, lane);
  WAIT_LGKM(); BARRIER();            // hL published

  // ===== Layer 2: 8 chunks, KC=32, barrier-free, 3-buf wS, VM(8) =====
  HID_ST(0, wH0, w2s, 3);
  HID_ST(1, wH1, w2s, 4);
  HID_ST(2, wH2, w2s, 5);
  HID_ST(3, wH0, w2s, 6);
  HID_ST(4, wH1, w2s, 7);
  HID_ST(5, wH2, w3s, 0);            // cross into W3 prefetch
  HID_ST(6, wH0, w3s, 1);
  HID_ST(7, wH1, w3s, 2);
  BARRIER();                         // all waves done reading hL
  silu_store(acc, b2g + s * HID, hL, w, lane);
  zero_acc(acc);
  WAIT_LGKM(); BARRIER();            // hL published

  // ===== Layer 3: 8 chunks; in flight: 0(wH2),1(wH0),2(wH1) =====
  HID_ST(0, wH2, w3s, 3);
  HID_ST(1, wH0, w3s, 4);
  HID_ST(2, wH1, w3s, 5);
  HID_ST(3, wH2, w3s, 6);
  HID_ST(4, wH0, w3s, 7);
  { WAIT_VM(8); SCHED0(); mfma32_h(acc, hL, 5, wH1, w, g, l15); }
  { WAIT_VM(4); SCHED0(); mfma32_h(acc, hL, 6, wH2, w, g, l15); }
  { WAIT_VM(0); SCHED0(); mfma32_h(acc, hL, 7, wH0, w, g, l15); }
  BARRIER();                         // all hidden-layer LDS reads complete

  // ===== Fused L3-silu + L4 dot + segment-sum (no hL round-trip) =====
  {
    // b3/w4 loaded here (after the last VM-counted region) so the hidden
    // VM(N) ledgers above stay exact. L2-hot: shared by all blocks.
    const float* b3 = b3g + s * HID;
    const float* w4 = w4g + s * HID;
    float b3v[4], w4v[4];
    #pragma unroll
    for (int bt = 0; bt < 4; ++bt) {
      const int col = w * 64 + bt * 16 + l15;
      b3v[bt] = b3[col];
      w4v[bt] = w4[col];
    }
    // Per-lane: fold silu(acc+b3)*w4 over this lane's 4 cols, for each of
    // its 16 rows (row = at*16 + g*4 + j, m89-verified C/D mapping).
    // shfl_xor over bits 0-3 reduces across l15 within the g-group
    // (lane = g*16 + l15, masks <16 stay in-group).
    float part[4][4];
    #pragma unroll
    for (int at = 0; at < 4; ++at) {
      #pragma unroll
      for (int j = 0; j < 4; ++j) {
        float sum = 0.f;
        #pragma unroll
        for (int bt = 0; bt < 4; ++bt) {
          float x = acc[at][bt][j] + b3v[bt];
          x = x * __builtin_amdgcn_rcpf(1.f + __expf(-x));
          sum += x * w4v[bt];
        }
        sum += __shfl_xor(sum, 1);
        sum += __shfl_xor(sum, 2);
        sum += __shfl_xor(sum, 4);
        sum += __shfl_xor(sum, 8);
        part[at][j] = sum;
      }
    }
    // Per-wave row sums -> 1 KB of dead LDS (all hidden buffers retired).
    float* redS = (float*)arena;     // [4 waves][64 rows]
    if (l15 == 0) {
      #pragma unroll
      for (int at = 0; at < 4; ++at)
        #pragma unroll
        for (int j = 0; j < 4; ++j)
          redS[w * 64 + at * 16 + g * 4 + j] = part[at][j];
    }
    WAIT_LGKM(); BARRIER();
    if (t < TM) {
      const int grL = row0 + t;
      if (grL < NPER) {
        const float e = redS[t] + redS[64 + t] + redS[128 + t] + redS[192 + t]
                      + b4g[s];
        atomicAdd(&outg[sidxg[s * NPER + grL]], e);
      }
    }
  }
}

// ---------------------------------------------------------------------------
extern "C" void kernel_launch(void* const* d_in, const int* in_sizes, int n_in,
                              void* d_out, int out_size, void* d_ws, size_t ws_size,
                              hipStream_t stream)
{
  const float* feats = (const float*)d_in[0];
  const float* W1    = (const float*)d_in[1];
  const float* b1    = (const float*)d_in[2];
  const float* W2    = (const float*)d_in[3];
  const float* b2    = (const float*)d_in[4];
  const float* W3    = (const float*)d_in[5];
  const float* b3    = (const float*)d_in[6];
  const float* W4    = (const float*)d_in[7];
  const float* b4    = (const float*)d_in[8];
  const int*   sidx  = (const int*)d_in[9];
  float* out = (float*)d_out;

  f16* w1t = (f16*)d_ws;                              // [S][256][1024] fp16
  f16* w2t = w1t + (size_t)S_ * HID * NF;             // [S][256][256]  fp16
  f16* w3t = w2t + (size_t)S_ * HID * HID;            // [S][256][256]  fp16

  hipMemsetAsync(d_out, 0, NSTRUCT * sizeof(float), stream);
  transpose_all_kernel<<<dim3(16, 4, 12), 256, 0, stream>>>(W1, W2, W3, w1t, w2t, w3t);
  mlp_fused_kernel<<<dim3((NPER + TM - 1) / TM, S_), 256, 0, stream>>>(
      feats, b1, b2, b3, W4, b4, sidx, w1t, w2t, w3t, out);
}

// Round 16
// 92.712 us; speedup vs baseline: 1.4917x; 1.0064x over previous
//
#include <hip/hip_runtime.h>

typedef _Float16 f16;
typedef __attribute__((ext_vector_type(8))) _Float16 f16x8;
typedef __attribute__((ext_vector_type(4))) float f32x4;
typedef unsigned int u32;

#define S_      4
#define NPER    12500
#define NF      1024
#define HID     256
#define NSTRUCT 500
#define TM      64

#define GLB __attribute__((address_space(1)))
#define AS3 __attribute__((address_space(3)))

#define WAIT_VM(N)  asm volatile("s_waitcnt vmcnt(" #N ")" ::: "memory")
#define WAIT_LGKM() asm volatile("s_waitcnt lgkmcnt(0)" ::: "memory")
#define SCHED0()    __builtin_amdgcn_sched_barrier(0)
#define BARRIER()   do { __builtin_amdgcn_s_barrier(); SCHED0(); } while (0)

// ---------------------------------------------------------------------------
// Fused weight transpose + fp32->fp16 (all 3 layers, 1 launch)
// ---------------------------------------------------------------------------
__global__ __launch_bounds__(256) void transpose_all_kernel(
    const float* __restrict__ W1, const float* __restrict__ W2,
    const float* __restrict__ W3,
    f16* __restrict__ w1t, f16* __restrict__ w2t, f16* __restrict__ w3t)
{
  const int z = blockIdx.z;            // layer*4 + species
  const int layer = z >> 2, sp = z & 3;
  const float* in; f16* out; int K;
  if (layer == 0)      { in = W1; out = w1t; K = NF;  }
  else if (layer == 1) { in = W2; out = w2t; K = HID; }
  else                 { in = W3; out = w3t; K = HID; }
  if (blockIdx.x * 64 >= K) return;

  __shared__ float tile[64][65];
  const float* inp = in + (size_t)sp * K * HID;
  f16* outp = out + (size_t)sp * K * HID;
  const int k0 = blockIdx.x * 64;
  const int n0 = blockIdx.y * 64;
  const int t = threadIdx.x;
  {
    const int lk = t >> 2;
    const int nq = (t & 3) * 16;
    const float* src = inp + (size_t)(k0 + lk) * HID + n0 + nq;
    #pragma unroll
    for (int i = 0; i < 4; ++i) {
      float4 v = *(const float4*)(src + i * 4);
      tile[lk][nq + i * 4 + 0] = v.x;
      tile[lk][nq + i * 4 + 1] = v.y;
      tile[lk][nq + i * 4 + 2] = v.z;
      tile[lk][nq + i * 4 + 3] = v.w;
    }
  }
  __syncthreads();
  {
    const int ln = t >> 2;
    const int kq = (t & 3) * 16;
    f16* dst = outp + (size_t)(n0 + ln) * K + k0 + kq;
    f16x8 a, b;
    #pragma unroll
    for (int j = 0; j < 8; ++j) a[j] = (f16)tile[kq + j][ln];
    #pragma unroll
    for (int j = 0; j < 8; ++j) b[j] = (f16)tile[kq + 8 + j][ln];
    *(f16x8*)dst = a;
    *(f16x8*)(dst + 8) = b;
  }
}

// ---------------------------------------------------------------------------
// Fused MLP FINAL = R22 (verified 93.3 us; session best, -15% vs baseline):
//  - L1: quad aS (4x8KB, barrier every 2 phases), single wave-private bS
//    32 KB staged after own lgkm-drain, 3-set pa rotation (distance 5),
//    steady VM(4).
//  - Hidden: wS 3-buffer gll rotation + VM(8), barrier-free inside layers.
//  - Fused L4 epilogue: silu+W4 dot in registers, shfl_xor reduce, 1 KB
//    LDS cross-wave sum, atomicAdd (removes the serialized hL round-trip
//    + uncovered w4 L2 reads -- the -11.2us win).
//  - TM=64 / (256,2): the only register-feasible fat-tile point (TM=80/96/
//    128 all spill or need order-pinning that costs more than it saves).
// ---------------------------------------------------------------------------

__device__ __forceinline__ void zero_acc(f32x4 (&acc)[4][4]) {
  #pragma unroll
  for (int a = 0; a < 4; ++a)
    #pragma unroll
    for (int b = 0; b < 4; ++b)
      #pragma unroll
      for (int j = 0; j < 4; ++j) acc[a][b][j] = 0.f;
}

// L1 weights: bS [256 n][8 slots of 16B]; phys slot p at row r holds k-slot
// p^(r&7). Wave w stages rows w*64..+63 -- exactly the rows it alone reads.
__device__ __forceinline__ void stage_w64(char* bS, const char* wbase, int c,
                                          int w, int lane)
{
  #pragma unroll
  for (int i = 0; i < 8; ++i) {
    const int seg  = w * 8 + i;                 // 0..31
    const int rloc = lane >> 3;                 // 0..7
    const int p    = lane & 7;                  // phys 16B slot
    const int row  = seg * 8 + rloc;            // 0..255
    const int slog = p ^ rloc;                  // logical k-slot (row&7 == rloc)
    const char* gp = wbase + (size_t)row * (NF * 2) + (size_t)c * 128 + slog * 16;
    char* lp = bS + seg * 1024;                 // wave-uniform base
    __builtin_amdgcn_global_load_lds((const GLB u32*)gp, (AS3 u32*)lp, 16, 0, 0);
  }
}

// Hidden weights: [256 n][32 k], phys slot = log ^ ((row>>1)&3). Self-staged.
__device__ __forceinline__ void stage_w32(char* wS, const char* wbase, int c,
                                          int w, int lane)
{
  #pragma unroll
  for (int i = 0; i < 4; ++i) {
    const int seg = w * 4 + i;                  // 0..15
    const int row = seg * 16 + (lane >> 2);     // 0..255
    const int kbp = lane & 3;
    const int kb  = kbp ^ ((row >> 1) & 3);
    const char* gp = wbase + (size_t)row * (HID * 2) + c * 64 + kb * 16;
    char* lp = wS + seg * 1024;
    __builtin_amdgcn_global_load_lds((const GLB u32*)gp, (AS3 u32*)lp, 16, 0, 0);
  }
}

__device__ __forceinline__ void load_pa(float4 (&pa)[4], const float* fsrcT, int c)
{
  #pragma unroll
  for (int j = 0; j < 4; ++j)
    pa[j] = *(const float4*)(fsrcT + c * 64 + j * 4);
}

// Features chunk [64 r][64 k] fp32->fp16 into aS (ds_write).
__device__ __forceinline__ void stage_feat64(char* aS, const float4 (&pa)[4], int t)
{
  const int r = t >> 2;
  #pragma unroll
  for (int wr = 0; wr < 2; ++wr) {
    f16x8 hv;
    const float4 lo = pa[wr * 2 + 0], hi = pa[wr * 2 + 1];
    hv[0]=(f16)lo.x; hv[1]=(f16)lo.y; hv[2]=(f16)lo.z; hv[3]=(f16)lo.w;
    hv[4]=(f16)hi.x; hv[5]=(f16)hi.y; hv[6]=(f16)hi.z; hv[7]=(f16)hi.w;
    const int slog = (t & 3) * 2 + wr;
    const int p = slog ^ (r & 7);
    *(f16x8*)(aS + r * 128 + p * 16) = hv;
  }
}

// L1 compute: one KC=64 chunk, 32 MFMA.
__device__ __forceinline__ void mfma64_a(f32x4 (&acc)[4][4], const char* aS,
                                         const char* bS, int w, int g, int l15)
{
  #pragma unroll
  for (int ks = 0; ks < 2; ++ks) {
    f16x8 af[4], bf[4];
    #pragma unroll
    for (int at = 0; at < 4; ++at) {
      const int rr = at * 16 + l15;
      const int p  = (ks * 4 + g) ^ (rr & 7);
      af[at] = *(const f16x8*)(aS + rr * 128 + p * 16);
    }
    #pragma unroll
    for (int bt = 0; bt < 4; ++bt) {
      const int nn = w * 64 + bt * 16 + l15;
      const int p  = (ks * 4 + g) ^ (nn & 7);
      bf[bt] = *(const f16x8*)(bS + nn * 128 + p * 16);
    }
    #pragma unroll
    for (int at = 0; at < 4; ++at)
      #pragma unroll
      for (int bt = 0; bt < 4; ++bt)
        acc[at][bt] = __builtin_amdgcn_mfma_f32_16x16x32_f16(af[at], bf[bt], acc[at][bt], 0, 0, 0);
  }
}

// Hidden compute: one KC=32 chunk, 16 MFMA.
__device__ __forceinline__ void mfma32_h(f32x4 (&acc)[4][4], const char* hL, int c,
                                         const char* wS, int w, int g, int l15)
{
  f16x8 af[4], bf[4];
  #pragma unroll
  for (int at = 0; at < 4; ++at) {
    const int rr = at * 16 + l15;
    af[at] = *(const f16x8*)(hL + ((rr * 512 + c * 64 + g * 16) ^ ((rr & 7) << 4)));
  }
  #pragma unroll
  for (int bt = 0; bt < 4; ++bt) {
    const int nn = w * 64 + bt * 16 + l15;
    bf[bt] = *(const f16x8*)(wS + nn * 64 + ((g ^ ((nn >> 1) & 3)) * 16));
  }
  #pragma unroll
  for (int at = 0; at < 4; ++at)
    #pragma unroll
    for (int bt = 0; bt < 4; ++bt)
      acc[at][bt] = __builtin_amdgcn_mfma_f32_16x16x32_f16(af[at], bf[bt], acc[at][bt], 0, 0, 0);
}

__device__ __forceinline__ void silu_store(f32x4 (&acc)[4][4],
                                           const float* __restrict__ bias,
                                           char* hL, int w, int lane)
{
  const int g = lane >> 4, l15 = lane & 15;
  #pragma unroll
  for (int bt = 0; bt < 4; ++bt) {
    const int col = w * 64 + bt * 16 + l15;
    const float b = bias[col];
    #pragma unroll
    for (int at = 0; at < 4; ++at) {
      #pragma unroll
      for (int j = 0; j < 4; ++j) {
        const int row = at * 16 + g * 4 + j;   // m89-verified C/D mapping
        float x = acc[at][bt][j] + b;
        x = x * __builtin_amdgcn_rcpf(1.f + __expf(-x));
        *(f16*)(hL + (((row * HID + col) * 2) ^ ((row & 7) << 4))) = (f16)x;
      }
    }
  }
}

// aS quad-buffer select (8 KB each)
#define ASB(c) (arena + (((c) & 3) << 13))

// L1 phase c: VM forces own gll(c); compute chunk c; lgkm retires own
// ds_reads (WAR gate for the single-bS overwrite); gll W1(c+1) into own
// slice; stage feat(c+2) into quad slot; refill pa(c+5); barrier only on
// odd phases (publishes the two A tiles staged since the last barrier).
#define L1_STEP(c, PAset, VMN, DOG, DOF, DOPA, DOBAR)            \
  do {                                                           \
    WAIT_VM(VMN); SCHED0();                                      \
    mfma64_a(acc, ASB(c), bS, w, g, l15);                        \
    WAIT_LGKM(); SCHED0();                                       \
    if (DOG)  stage_w64(bS, w1s, (c) + 1, w, lane);              \
    if (DOF)  stage_feat64(ASB((c) + 2), PAset, t);              \
    if (DOPA) load_pa(PAset, fsrcT, (c) + 5);                    \
    if (DOBAR) { WAIT_LGKM(); BARRIER(); }                       \
  } while (0)

// Hidden step: counted wait readies chunk c, compute, drain own reads,
// stage chunk c+3 into the buffer just freed. Barrier-free.
#define HID_ST(c, WSc, wsrc, cs)                                 \
  do {                                                           \
    WAIT_VM(8); SCHED0();                                        \
    mfma32_h(acc, hL, c, WSc, w, g, l15);                        \
    WAIT_LGKM(); SCHED0();                                       \
    stage_w32(WSc, wsrc, cs, w, lane);                           \
  } while (0)

__global__ __launch_bounds__(256, 2) void mlp_fused_kernel(
    const float* __restrict__ feats,
    const float* __restrict__ b1g,
    const float* __restrict__ b2g,
    const float* __restrict__ b3g,
    const float* __restrict__ w4g,
    const float* __restrict__ b4g,
    const int*   __restrict__ sidxg,
    const f16*   __restrict__ w1t,
    const f16*   __restrict__ w2t,
    const f16*   __restrict__ w3t,
    float*       __restrict__ outg)
{
  __shared__ char arena[80 * 1024];
  char* bS  = arena + 32 * 1024;     // L1 weights: single 32 KB (wave-private)
  char* hL  = arena;                 // hidden: h [64][256] fp16, 32 KB overlay
  char* wH0 = arena + 64 * 1024;     // hidden weights rotation: 3 x 16 KB
  char* wH1 = arena + 32 * 1024;     //   (wH0 free at ph15; wH1/wH2 over bS)
  char* wH2 = arena + 48 * 1024;

  const int s    = blockIdx.y;
  const int row0 = blockIdx.x * TM;
  const int t    = threadIdx.x;
  const int lane = t & 63;
  const int w    = t >> 6;           // 0..3; wave w owns output cols w*64..+63
  const int g    = lane >> 4;
  const int l15  = lane & 15;

  const int gr   = row0 + (t >> 2);
  const bool valid = gr < NPER;
  const int grc  = valid ? gr : (NPER - 1);
  const float* fsrcT = feats + ((size_t)s * NPER + grc) * NF + (t & 3) * 16;
  const char*  w1s   = (const char*)(w1t + (size_t)s * HID * NF);
  const char*  w2s   = (const char*)(w2t + (size_t)s * HID * HID);
  const char*  w3s   = (const char*)(w3t + (size_t)s * HID * HID);

  f32x4 acc[4][4];
  zero_acc(acc);

  // ===== L1 prologue: aS(0),aS(1) staged; gll(0); pa(2..4) in 3 sets =====
  float4 pf0[4], pf1[4], paA[4], paB[4], paC[4];
  load_pa(pf0, fsrcT, 0);
  load_pa(pf1, fsrcT, 1);
  stage_w64(bS, w1s, 0, w, lane);
  load_pa(paA, fsrcT, 2);
  load_pa(paB, fsrcT, 3);
  load_pa(paC, fsrcT, 4);
  stage_feat64(ASB(0), pf0, t);      // compiler waits pf0 only (keeps gll/pa)
  stage_feat64(ASB(1), pf1, t);      // compiler waits pf1 only
  WAIT_LGKM(); BARRIER();            // publish aS(0), aS(1)

  // ===== L1: 16 phases, KC=64, quad aS, single bS, barrier every 2 =====
  // Set map: phase c consumes pa(c+2) from set[c%3], reloads it <- pa(c+5).
  L1_STEP(0,  paA, 12, 1, 1, 1, 0);
  L1_STEP(1,  paB,  4, 1, 1, 1, 1);
  L1_STEP(2,  paC,  4, 1, 1, 1, 0);
  L1_STEP(3,  paA,  4, 1, 1, 1, 1);
  L1_STEP(4,  paB,  4, 1, 1, 1, 0);
  L1_STEP(5,  paC,  4, 1, 1, 1, 1);
  L1_STEP(6,  paA,  4, 1, 1, 1, 0);
  L1_STEP(7,  paB,  4, 1, 1, 1, 1);
  L1_STEP(8,  paC,  4, 1, 1, 1, 0);
  L1_STEP(9,  paA,  4, 1, 1, 1, 1);
  L1_STEP(10, paB,  4, 1, 1, 1, 0);  // loads pa(15) -> paB (last pa)
  L1_STEP(11, paC,  4, 1, 1, 0, 1);  // stage aS(13)
  L1_STEP(12, paA,  0, 1, 1, 0, 0);  // stage aS(14) from pa(14)=paA
  L1_STEP(13, paB,  0, 1, 1, 0, 1);  // stage aS(15) from pa(15)=paB
  L1_STEP(14, paC,  0, 1, 0, 0, 0);  // gll(15); no more feat staging
  { // phase 15: last chunk; early-stage W2 chunk0 into wH0 (free region)
    WAIT_VM(0); SCHED0();
    mfma64_a(acc, ASB(15), bS, w, g, l15);
    WAIT_LGKM(); SCHED0();
    stage_w32(wH0, w2s, 0, w, lane);
    WAIT_LGKM(); BARRIER();          // all aS/bS reads done block-wide
  }

  // ===== L1 -> L2: h over dead aS; fill wS pipeline over dead bS =====
  silu_store(acc, b1g + s * HID, hL, w, lane);
  zero_acc(acc);
  stage_w32(wH1, w2s, 1, w, lane);
  stage_w32(wH2, w2s, 2, w, lane);
  WAIT_LGKM(); BARRIER();            // hL published

  // ===== Layer 2: 8 chunks, KC=32, barrier-free, 3-buf wS, VM(8) =====
  HID_ST(0, wH0, w2s, 3);
  HID_ST(1, wH1, w2s, 4);
  HID_ST(2, wH2, w2s, 5);
  HID_ST(3, wH0, w2s, 6);
  HID_ST(4, wH1, w2s, 7);
  HID_ST(5, wH2, w3s, 0);            // cross into W3 prefetch
  HID_ST(6, wH0, w3s, 1);
  HID_ST(7, wH1, w3s, 2);
  BARRIER();                         // all waves done reading hL
  silu_store(acc, b2g + s * HID, hL, w, lane);
  zero_acc(acc);
  WAIT_LGKM(); BARRIER();            // hL published

  // ===== Layer 3: 8 chunks; in flight: 0(wH2),1(wH0),2(wH1) =====
  HID_ST(0, wH2, w3s, 3);
  HID_ST(1, wH0, w3s, 4);
  HID_ST(2, wH1, w3s, 5);
  HID_ST(3, wH2, w3s, 6);
  HID_ST(4, wH0, w3s, 7);
  { WAIT_VM(8); SCHED0(); mfma32_h(acc, hL, 5, wH1, w, g, l15); }
  { WAIT_VM(4); SCHED0(); mfma32_h(acc, hL, 6, wH2, w, g, l15); }
  { WAIT_VM(0); SCHED0(); mfma32_h(acc, hL, 7, wH0, w, g, l15); }
  BARRIER();                         // all hidden-layer LDS reads complete

  // ===== Fused L3-silu + L4 dot + segment-sum (no hL round-trip) =====
  {
    // b3/w4 loaded here (after the last VM-counted region) so the hidden
    // VM(N) ledgers above stay exact. L2-hot: shared by all blocks.
    const float* b3 = b3g + s * HID;
    const float* w4 = w4g + s * HID;
    float b3v[4], w4v[4];
    #pragma unroll
    for (int bt = 0; bt < 4; ++bt) {
      const int col = w * 64 + bt * 16 + l15;
      b3v[bt] = b3[col];
      w4v[bt] = w4[col];
    }
    // Per-lane: fold silu(acc+b3)*w4 over this lane's 4 cols, for each of
    // its 16 rows (row = at*16 + g*4 + j, m89-verified C/D mapping).
    // shfl_xor over bits 0-3 reduces across l15 within the g-group
    // (lane = g*16 + l15, masks <16 stay in-group).
    float part[4][4];
    #pragma unroll
    for (int at = 0; at < 4; ++at) {
      #pragma unroll
      for (int j = 0; j < 4; ++j) {
        float sum = 0.f;
        #pragma unroll
        for (int bt = 0; bt < 4; ++bt) {
          float x = acc[at][bt][j] + b3v[bt];
          x = x * __builtin_amdgcn_rcpf(1.f + __expf(-x));
          sum += x * w4v[bt];
        }
        sum += __shfl_xor(sum, 1);
        sum += __shfl_xor(sum, 2);
        sum += __shfl_xor(sum, 4);
        sum += __shfl_xor(sum, 8);
        part[at][j] = sum;
      }
    }
    // Per-wave row sums -> 1 KB of dead LDS (all hidden buffers retired).
    float* redS = (float*)arena;     // [4 waves][64 rows]
    if (l15 == 0) {
      #pragma unroll
      for (int at = 0; at < 4; ++at)
        #pragma unroll
        for (int j = 0; j < 4; ++j)
          redS[w * 64 + at * 16 + g * 4 + j] = part[at][j];
    }
    WAIT_LGKM(); BARRIER();
    if (t < TM) {
      const int grL = row0 + t;
      if (grL < NPER) {
        const float e = redS[t] + redS[64 + t] + redS[128 + t] + redS[192 + t]
                      + b4g[s];
        atomicAdd(&outg[sidxg[s * NPER + grL]], e);
      }
    }
  }
}

// ---------------------------------------------------------------------------
extern "C" void kernel_launch(void* const* d_in, const int* in_sizes, int n_in,
                              void* d_out, int out_size, void* d_ws, size_t ws_size,
                              hipStream_t stream)
{
  const float* feats = (const float*)d_in[0];
  const float* W1    = (const float*)d_in[1];
  const float* b1    = (const float*)d_in[2];
  const float* W2    = (const float*)d_in[3];
  const float* b2    = (const float*)d_in[4];
  const float* W3    = (const float*)d_in[5];
  const float* b3    = (const float*)d_in[6];
  const float* W4    = (const float*)d_in[7];
  const float* b4    = (const float*)d_in[8];
  const int*   sidx  = (const int*)d_in[9];
  float* out = (float*)d_out;

  f16* w1t = (f16*)d_ws;                              // [S][256][1024] fp16
  f16* w2t = w1t + (size_t)S_ * HID * NF;             // [S][256][256]  fp16
  f16* w3t = w2t + (size_t)S_ * HID * HID;            // [S][256][256]  fp16

  hipMemsetAsync(d_out, 0, NSTRUCT * sizeof(float), stream);
  transpose_all_kernel<<<dim3(16, 4, 12), 256, 0, stream>>>(W1, W2, W3, w1t, w2t, w3t);
  mlp_fused_kernel<<<dim3((NPER + TM - 1) / TM, S_), 256, 0, stream>>>(
      feats, b1, b2, b3, W4, b4, sidx, w1t, w2t, w3t, out);
}